// Round 10
// baseline (141.976 us; speedup 1.0000x reference)
//
#include <hip/hip_runtime.h>
#include <math.h>

typedef unsigned short u16;
typedef unsigned int   u32;

#define B_       64
#define NN_      64
#define HL_      50
#define IN_DIM   384
#define POS_DIM  64
#define ATT_DIM  256
#define NEWS_DIM 448   // IN_DIM + POS_DIM

typedef __attribute__((ext_vector_type(8))) short short8;   // bf16x8 MFMA frag
typedef __attribute__((ext_vector_type(4))) float f32x4;    // MFMA acc

#if __has_builtin(__builtin_amdgcn_exp2f)
#define EXP2F(x) __builtin_amdgcn_exp2f(x)
#else
#define EXP2F(x) exp2f(x)
#endif
#if __has_builtin(__builtin_amdgcn_rcpf)
#define RCPF(x) __builtin_amdgcn_rcpf(x)
#else
#define RCPF(x) (1.0f/(x))
#endif

__device__ __forceinline__ u16 f2bf(float f) {
    union { float f; u32 i; } v; v.f = f;
    u32 r = v.i + 0x7fffu + ((v.i >> 16) & 1u);   // RNE
    return (u16)(r >> 16);
}
__device__ __forceinline__ float bf2f(u16 u) {
    union { u32 i; float f; } v; v.i = ((u32)u) << 16; return v.f;
}
__device__ __forceinline__ uint2 pack4(float4 v) {
    return make_uint2((u32)f2bf(v.x) | ((u32)f2bf(v.y) << 16),
                      (u32)f2bf(v.z) | ((u32)f2bf(v.w) << 16));
}
// tanh(x) = 1 - 2/(1+2^(x*2*log2e)); v_exp+v_rcp saturate correctly at +-inf.
__device__ __forceinline__ float fast_tanh(float x) {
    float e = EXP2F(x * 2.88539008f);
    return 1.0f - 2.0f * RCPF(1.0f + e);
}

// prep segments, in 4-f32 chunks
#define C_W   57344u     // W1 (256x896) -> Wbf
#define C_NV  393216u    // newsv (4096x384) -> nv_bf AND nf f32 head
#define C_LG  307200u    // logv (3200x384) -> lf_bf head
#define C_PS  51200u     // pos rows 1..50 -> lf_bf tail
#define C_NZ  65536u     // nf f32 zero tail (4096x64)
#define C_TOT (C_W + C_NV + C_LG + C_PS + C_NZ)   // 874,496 = 3416*256

// ---------------- K0: bf16-convert W1/newsv/lf into ws; nf (f32) -> d_out.
__global__ __launch_bounds__(256) void prep_k(
    const float* __restrict__ W1, const float* __restrict__ newsv,
    const float* __restrict__ logv, const float* __restrict__ pos,
    u16* __restrict__ Wbf, u16* __restrict__ nv_bf, u16* __restrict__ lf_bf,
    float* __restrict__ nf)
{
    u32 i = blockIdx.x * 256u + threadIdx.x;
    if (i < C_W) {                                   // W1 -> Wbf
        float4 v = *(const float4*)(W1 + (size_t)i * 4u);
        *(uint2*)(Wbf + (size_t)i * 4u) = pack4(v);
        return;
    }
    i -= C_W;
    if (i < C_NV) {                                  // newsv -> nv_bf + nf head
        float4 v = *(const float4*)(newsv + (size_t)i * 4u);
        *(uint2*)(nv_bf + (size_t)i * 4u) = pack4(v);
        u32 e = i * 4u, r = e / IN_DIM, d = e - r * IN_DIM;
        *(float4*)(nf + (size_t)r * NEWS_DIM + d) = v;
        return;
    }
    i -= C_NV;
    if (i < C_LG) {                                  // logv -> lf_bf head
        float4 v = *(const float4*)(logv + (size_t)i * 4u);
        u32 e = i * 4u, r = e / IN_DIM, d = e - r * IN_DIM;
        *(uint2*)(lf_bf + (size_t)r * NEWS_DIM + d) = pack4(v);
        return;
    }
    i -= C_LG;
    if (i < C_PS) {                                  // pos rows 1..50 -> lf_bf tail
        u32 e = i * 4u, r = e / POS_DIM, d = e - r * POS_DIM;
        u32 h = r % HL_;
        float4 v = *(const float4*)(pos + (size_t)(1u + h) * POS_DIM + d);
        *(uint2*)(lf_bf + (size_t)r * NEWS_DIM + IN_DIM + d) = pack4(v);
        return;
    }
    i -= C_PS;
    if (i < C_NZ) {                                  // nf zero tail
        u32 e = i * 4u, r = e / POS_DIM, d = e - r * POS_DIM;
        *(float4*)(nf + (size_t)r * NEWS_DIM + IN_DIM + d) = make_float4(0.f, 0.f, 0.f, 0.f);
    }
}

// ---------------- K1: fused NT GEMMs, 32x64 tiles (2x4 acc) for occupancy:
// 912 one-wave blocks ~= 3.6 waves/CU (was 456 ~= 1.8 -- latency-exposed).
// bid < 512: pn[4096x256] = nv_bf . Wbf[:, :384]^T + b1
// bid >= 512: plT[(b*256+a)*50+h] = lf_bf . Wbf[:, 448:]^T  (transposed store)
__global__ __launch_bounds__(64) void gemm_k(
    const u16* __restrict__ nv_bf, const u16* __restrict__ lf_bf,
    const u16* __restrict__ Wbf, const float* __restrict__ b1,
    float* __restrict__ pn, float* __restrict__ plT)
{
    int bid = blockIdx.x;
    int lane = threadIdx.x;
    int m = lane & 15, q = lane >> 4;
    bool is_pn = bid < 512;
    int r0, c0, lda, koff, klen;
    const u16* A;
    if (is_pn) { r0 = (bid >> 2) * 32; c0 = (bid & 3) * 64; A = nv_bf; lda = IN_DIM;   koff = 0;        klen = IN_DIM; }
    else { int b2 = bid - 512; r0 = (b2 >> 2) * 32; c0 = (b2 & 3) * 64; A = lf_bf; lda = NEWS_DIM; koff = NEWS_DIM; klen = NEWS_DIM; }

    f32x4 acc[2][4];
#pragma unroll
    for (int a = 0; a < 2; a++)
#pragma unroll
        for (int b = 0; b < 4; b++) acc[a][b] = (f32x4){0.f, 0.f, 0.f, 0.f};

    const u16* Ap = A + (size_t)(r0 + m) * lda + q * 8;
    const u16* Wp = Wbf + (size_t)(c0 + m) * (2 * NEWS_DIM) + koff + q * 8;

    for (int k = 0; k < klen; k += 32) {
        short8 af[2], wf[4];
#pragma unroll
        for (int rt = 0; rt < 2; rt++) af[rt] = *(const short8*)(Ap + rt * 16 * lda + k);
#pragma unroll
        for (int ct = 0; ct < 4; ct++) wf[ct] = *(const short8*)(Wp + ct * 16 * (2 * NEWS_DIM) + k);
#pragma unroll
        for (int rt = 0; rt < 2; rt++)
#pragma unroll
            for (int ct = 0; ct < 4; ct++)
                acc[rt][ct] = __builtin_amdgcn_mfma_f32_16x16x32_bf16(
                    af[rt], wf[ct], acc[rt][ct], 0, 0, 0);
    }
    // C/D layout: col = lane&15, row = (lane>>4)*4 + i  [m89]
#pragma unroll
    for (int rt = 0; rt < 2; rt++)
#pragma unroll
        for (int ct = 0; ct < 4; ct++)
#pragma unroll
            for (int i = 0; i < 4; i++) {
                int gr = r0 + rt * 16 + q * 4 + i;
                int gc = c0 + ct * 16 + m;
                float v = acc[rt][ct][i];
                if (is_pn) {
                    pn[(size_t)gr * ATT_DIM + gc] = v + b1[gc];
                } else {
                    int bb = gr / HL_, hh = gr - bb * HL_;
                    plT[(size_t)(bb * ATT_DIM + gc) * HL_ + hh] = v;
                }
            }
}

// ---------------- K2: FUSED logits -> masked softmax -> out = attn x lf.
// All 4 waves of a block share b (8 blocks per b); plT[b] staged through LDS
// in 8 chunks of 32 a x 64 h -> pl L2 traffic cut 32x; pl_s[a][lane] is
// 2-way bank aliasing = free (m136). Trans pipe is then the only floor.
__global__ __launch_bounds__(256) void attn_out_k(
    const float* __restrict__ pn, const float* __restrict__ plT,
    const float* __restrict__ w2, const int* __restrict__ lmask,
    const u16* __restrict__ lf_bf, float* __restrict__ out)
{
    __shared__ float pl_s[32][64];             // a-chunk x h(padded), 8 KB
    __shared__ float at_s[4][2][64];           // per-wave attn slices, 2 KB
    int tid = threadIdx.x;
    int lane = tid & 63;
    int wid = tid >> 6;
    int b = blockIdx.x >> 3;                   // 8 blocks per b
    int n0 = ((blockIdx.x & 7) * 4 + wid) * 2; // n-pair per wave
    const float* pr0 = pn + ((size_t)b * NN_ + n0) * ATT_DIM;
    const float* pr1 = pr0 + ATT_DIM;
    const float* plb = plT + (size_t)b * ATT_DIM * HL_;

    float a00 = 0.f, a01 = 0.f, a10 = 0.f, a11 = 0.f;
    for (int ac = 0; ac < ATT_DIM; ac += 32) {
        __syncthreads();                       // previous chunk fully consumed
        for (int i = tid; i < 32 * 64; i += 256) {
            int a = i >> 6, h = i & 63;
            pl_s[a][h] = (h < HL_) ? plb[(size_t)(ac + a) * HL_ + h] : 0.f;
        }
        __syncthreads();
#pragma unroll 2
        for (int a = 0; a < 32; a += 4) {
            float4 w4 = *(const float4*)(w2 + ac + a);
            float4 p0 = *(const float4*)(pr0 + ac + a);
            float4 p1 = *(const float4*)(pr1 + ac + a);
            float l0 = pl_s[a + 0][lane];
            float l1 = pl_s[a + 1][lane];
            float l2 = pl_s[a + 2][lane];
            float l3 = pl_s[a + 3][lane];
            a00 = __builtin_fmaf(fast_tanh(p0.x + l0), w4.x, a00);
            a10 = __builtin_fmaf(fast_tanh(p1.x + l0), w4.x, a10);
            a01 = __builtin_fmaf(fast_tanh(p0.y + l1), w4.y, a01);
            a11 = __builtin_fmaf(fast_tanh(p1.y + l1), w4.y, a11);
            a00 = __builtin_fmaf(fast_tanh(p0.z + l2), w4.z, a00);
            a10 = __builtin_fmaf(fast_tanh(p1.z + l2), w4.z, a10);
            a01 = __builtin_fmaf(fast_tanh(p0.w + l3), w4.w, a01);
            a11 = __builtin_fmaf(fast_tanh(p1.w + l3), w4.w, a11);
        }
    }
    float acc0 = a00 + a01, acc1 = a10 + a11;
    int mv = (lane < HL_) ? lmask[b * HL_ + lane] : 0;
    float lg0 = mv ? acc0 : -1e9f;             // b2 dropped: softmax-invariant
    float lg1 = mv ? acc1 : -1e9f;
    float mx0 = lg0, mx1 = lg1;
#pragma unroll
    for (int o = 32; o > 0; o >>= 1) {
        mx0 = fmaxf(mx0, __shfl_xor(mx0, o));
        mx1 = fmaxf(mx1, __shfl_xor(mx1, o));
    }
    float e0 = EXP2F((lg0 - mx0) * 1.44269504f);   // masked lanes -> 0
    float e1 = EXP2F((lg1 - mx1) * 1.44269504f);
    float s0 = e0, s1 = e1;
#pragma unroll
    for (int o = 32; o > 0; o >>= 1) {
        s0 += __shfl_xor(s0, o);
        s1 += __shfl_xor(s1, o);
    }
    at_s[wid][0][lane] = e0 * RCPF(s0);
    at_s[wid][1][lane] = e1 * RCPF(s1);
    // no barrier: same wave writes & reads its own slice (lgkmcnt enforced)

    // phase 2: out[b, n0+n][d], d = lane + 64j (j<7); lf rows coalesced 128B.
    const u16* lfb = lf_bf + (size_t)b * HL_ * NEWS_DIM + lane;
    float acc[2][7];
#pragma unroll
    for (int j = 0; j < 7; j++) { acc[0][j] = 0.f; acc[1][j] = 0.f; }
    for (int h = 0; h < HL_; h++) {
        float v0 = at_s[wid][0][h];            // LDS broadcast
        float v1 = at_s[wid][1][h];
        const u16* row = lfb + (size_t)h * NEWS_DIM;
#pragma unroll
        for (int j = 0; j < 7; j++) {
            float lv = bf2f(row[64 * j]);
            acc[0][j] = fmaf(v0, lv, acc[0][j]);
            acc[1][j] = fmaf(v1, lv, acc[1][j]);
        }
    }
    float* o0 = out + ((size_t)b * NN_ + n0) * NEWS_DIM + lane;
#pragma unroll
    for (int j = 0; j < 7; j++) {
        o0[64 * j] = acc[0][j];
        o0[NEWS_DIM + 64 * j] = acc[1][j];
    }
}

extern "C" void kernel_launch(void* const* d_in, const int* in_sizes, int n_in,
                              void* d_out, int out_size, void* d_ws, size_t ws_size,
                              hipStream_t stream) {
    const float* logv  = (const float*)d_in[0];  // (64,50,384) f32
    const int*   lmask = (const int*)d_in[1];    // (64,50) i32
    const float* newsv = (const float*)d_in[2];  // (64,64,384) f32
    const float* pos   = (const float*)d_in[3];  // (100,64) f32; row 0 == 0
    const float* W1    = (const float*)d_in[4];  // (256,896) f32
    const float* b1    = (const float*)d_in[5];  // (256,) f32
    const float* w2    = (const float*)d_in[6];  // (1,256) f32
    // b2 unused (softmax-invariant shift)

    float* out = (float*)d_out;                  // [user_log | nf], f32
    float* nf  = out + (size_t)B_ * NN_ * NEWS_DIM;

    // d_ws ~256 MiB. Byte offsets, 16B aligned:
    char* ws = (char*)d_ws;
    u16*   lf_bf = (u16*)(ws + 0);               // 3200x448 bf16  (2,867,200 B)
    u16*   Wbf   = (u16*)(ws + 2867200);         // 256x896 bf16   (458,752 B)
    u16*   nv_bf = (u16*)(ws + 3325952);         // 4096x384 bf16  (3,145,728 B)
    float* pn    = (float*)(ws + 6471680);       // 4096x256 f32   (4,194,304 B)
    float* plT   = (float*)(ws + 10665984);      // 64x256x50 f32  (3,276,800 B)

    prep_k    <<<C_TOT / 256, 256, 0, stream>>>(W1, newsv, logv, pos,
                                                Wbf, nv_bf, lf_bf, nf);
    gemm_k    <<<912, 64, 0, stream>>>(nv_bf, lf_bf, Wbf, b1, pn, plT);
    attn_out_k<<<512, 256, 0, stream>>>(pn, plT, w2, lmask, lf_bf, out);
}

// Round 11
// 132.092 us; speedup vs baseline: 1.0748x; 1.0748x over previous
//
#include <hip/hip_runtime.h>
#include <math.h>

typedef unsigned short u16;
typedef unsigned int   u32;

#define B_       64
#define NN_      64
#define HL_      50
#define IN_DIM   384
#define POS_DIM  64
#define ATT_DIM  256
#define NEWS_DIM 448   // IN_DIM + POS_DIM

typedef __attribute__((ext_vector_type(8))) short short8;   // bf16x8 MFMA frag
typedef __attribute__((ext_vector_type(4))) float f32x4;    // MFMA acc

#if __has_builtin(__builtin_amdgcn_exp2f)
#define EXP2F(x) __builtin_amdgcn_exp2f(x)
#else
#define EXP2F(x) exp2f(x)
#endif
#if __has_builtin(__builtin_amdgcn_rcpf)
#define RCPF(x) __builtin_amdgcn_rcpf(x)
#else
#define RCPF(x) (1.0f/(x))
#endif

__device__ __forceinline__ u16 f2bf(float f) {
    union { float f; u32 i; } v; v.f = f;
    u32 r = v.i + 0x7fffu + ((v.i >> 16) & 1u);   // RNE
    return (u16)(r >> 16);
}
__device__ __forceinline__ float bf2f(u16 u) {
    union { u32 i; float f; } v; v.i = ((u32)u) << 16; return v.f;
}
__device__ __forceinline__ uint2 pack4(float4 v) {
    return make_uint2((u32)f2bf(v.x) | ((u32)f2bf(v.y) << 16),
                      (u32)f2bf(v.z) | ((u32)f2bf(v.w) << 16));
}
// tanh(x) = 1 - 2/(1+2^(x*2*log2e)); v_exp+v_rcp saturate correctly at +-inf.
__device__ __forceinline__ float fast_tanh(float x) {
    float e = EXP2F(x * 2.88539008f);
    return 1.0f - 2.0f * RCPF(1.0f + e);
}

// prep segments, in 4-f32 chunks
#define C_W   57344u     // W1 (256x896) -> Wbf
#define C_NV  393216u    // newsv (4096x384) -> nv_bf AND nf f32 head
#define C_LG  307200u    // logv (3200x384) -> lf_bf head
#define C_PS  51200u     // pos rows 1..50 -> lf_bf tail
#define C_NZ  65536u     // nf f32 zero tail (4096x64)
#define C_TOT (C_W + C_NV + C_LG + C_PS + C_NZ)   // 874,496 = 3416*256

// ---------------- K0: bf16-convert W1/newsv/lf into ws; nf (f32) -> d_out.
__global__ __launch_bounds__(256) void prep_k(
    const float* __restrict__ W1, const float* __restrict__ newsv,
    const float* __restrict__ logv, const float* __restrict__ pos,
    u16* __restrict__ Wbf, u16* __restrict__ nv_bf, u16* __restrict__ lf_bf,
    float* __restrict__ nf)
{
    u32 i = blockIdx.x * 256u + threadIdx.x;
    if (i < C_W) {                                   // W1 -> Wbf
        float4 v = *(const float4*)(W1 + (size_t)i * 4u);
        *(uint2*)(Wbf + (size_t)i * 4u) = pack4(v);
        return;
    }
    i -= C_W;
    if (i < C_NV) {                                  // newsv -> nv_bf + nf head
        float4 v = *(const float4*)(newsv + (size_t)i * 4u);
        *(uint2*)(nv_bf + (size_t)i * 4u) = pack4(v);
        u32 e = i * 4u, r = e / IN_DIM, d = e - r * IN_DIM;
        *(float4*)(nf + (size_t)r * NEWS_DIM + d) = v;
        return;
    }
    i -= C_NV;
    if (i < C_LG) {                                  // logv -> lf_bf head
        float4 v = *(const float4*)(logv + (size_t)i * 4u);
        u32 e = i * 4u, r = e / IN_DIM, d = e - r * IN_DIM;
        *(uint2*)(lf_bf + (size_t)r * NEWS_DIM + d) = pack4(v);
        return;
    }
    i -= C_LG;
    if (i < C_PS) {                                  // pos rows 1..50 -> lf_bf tail
        u32 e = i * 4u, r = e / POS_DIM, d = e - r * POS_DIM;
        u32 h = r % HL_;
        float4 v = *(const float4*)(pos + (size_t)(1u + h) * POS_DIM + d);
        *(uint2*)(lf_bf + (size_t)r * NEWS_DIM + IN_DIM + d) = pack4(v);
        return;
    }
    i -= C_PS;
    if (i < C_NZ) {                                  // nf zero tail
        u32 e = i * 4u, r = e / POS_DIM, d = e - r * POS_DIM;
        *(float4*)(nf + (size_t)r * NEWS_DIM + IN_DIM + d) = make_float4(0.f, 0.f, 0.f, 0.f);
    }
}

// ---------------- K1: fused NT GEMMs, pure bf16 16B loads (R9-proven form).
// bid < 256: pn[4096x256] = nv_bf . Wbf[:, :384]^T + b1
// bid >= 256: plT[(b*256+a)*50+h] = lf_bf . Wbf[:, 448:]^T  (transposed store)
__global__ __launch_bounds__(64) void gemm_k(
    const u16* __restrict__ nv_bf, const u16* __restrict__ lf_bf,
    const u16* __restrict__ Wbf, const float* __restrict__ b1,
    float* __restrict__ pn, float* __restrict__ plT)
{
    int bid = blockIdx.x;
    int lane = threadIdx.x;
    int m = lane & 15, q = lane >> 4;
    bool is_pn = bid < 256;
    int r0, c0, lda, koff, klen;
    const u16* A;
    if (is_pn) { r0 = (bid & 63) * 64;       c0 = (bid >> 6) * 64; A = nv_bf; lda = IN_DIM;   koff = 0;        klen = IN_DIM; }
    else { int b2 = bid - 256; r0 = (b2 % 50) * 64; c0 = (b2 / 50) * 64; A = lf_bf; lda = NEWS_DIM; koff = NEWS_DIM; klen = NEWS_DIM; }

    f32x4 acc[4][4];
#pragma unroll
    for (int a = 0; a < 4; a++)
#pragma unroll
        for (int b = 0; b < 4; b++) acc[a][b] = (f32x4){0.f, 0.f, 0.f, 0.f};

    const u16* Ap = A + (size_t)(r0 + m) * lda + q * 8;
    const u16* Wp = Wbf + (size_t)(c0 + m) * (2 * NEWS_DIM) + koff + q * 8;

    for (int k = 0; k < klen; k += 32) {
        short8 af[4], wf[4];
#pragma unroll
        for (int rt = 0; rt < 4; rt++) af[rt] = *(const short8*)(Ap + rt * 16 * lda + k);
#pragma unroll
        for (int ct = 0; ct < 4; ct++) wf[ct] = *(const short8*)(Wp + ct * 16 * (2 * NEWS_DIM) + k);
#pragma unroll
        for (int rt = 0; rt < 4; rt++)
#pragma unroll
            for (int ct = 0; ct < 4; ct++)
                acc[rt][ct] = __builtin_amdgcn_mfma_f32_16x16x32_bf16(
                    af[rt], wf[ct], acc[rt][ct], 0, 0, 0);
    }
    // C/D layout: col = lane&15, row = (lane>>4)*4 + i  [m89]
#pragma unroll
    for (int rt = 0; rt < 4; rt++)
#pragma unroll
        for (int ct = 0; ct < 4; ct++)
#pragma unroll
            for (int i = 0; i < 4; i++) {
                int gr = r0 + rt * 16 + q * 4 + i;
                int gc = c0 + ct * 16 + m;
                float v = acc[rt][ct][i];
                if (is_pn) {
                    pn[(size_t)gr * ATT_DIM + gc] = v + b1[gc];
                } else {
                    int bb = gr / HL_, hh = gr - bb * HL_;
                    plT[(size_t)(bb * ATT_DIM + gc) * HL_ + hh] = v;
                }
            }
}

// ---------------- K2: FUSED logits -> masked softmax -> out = attn x lf.
// ONE WAVE PER (b,n): 4096 waves = 4/SIMD (R10's LDS-staged 2048-wave version
// measured 48us @ VALUBusy 34% / occupancy 17% -- latency-bound, not BW-bound;
// this doubles latency hiding and drops the barriers). Direct pl loads (L2-hit).
__global__ __launch_bounds__(256) void attn_out_k(
    const float* __restrict__ pn, const float* __restrict__ plT,
    const float* __restrict__ w2, const int* __restrict__ lmask,
    const u16* __restrict__ lf_bf, float* __restrict__ out)
{
    __shared__ float at_s[4][64];              // per-wave attn slices, 1 KB
    int lane = threadIdx.x & 63;
    int wid = (int)(threadIdx.x >> 6);
    int g = blockIdx.x * 4 + wid;              // wave id in [0,4096)
    int b = g >> 6;
    int n = g & 63;
    int hl = (lane < HL_) ? lane : (HL_ - 1);  // clamp reads
    const float* pr = pn + (size_t)g * ATT_DIM;
    const float* pl = plT + (size_t)b * ATT_DIM * HL_ + hl;

    float a0 = 0.f, a1 = 0.f, a2 = 0.f, a3 = 0.f;
#pragma unroll 4
    for (int a = 0; a < ATT_DIM; a += 4) {
        float4 w4 = *(const float4*)(w2 + a);
        float4 p  = *(const float4*)(pr + a);  // wave-uniform
        float l0 = pl[(a + 0) * HL_];
        float l1 = pl[(a + 1) * HL_];
        float l2 = pl[(a + 2) * HL_];
        float l3 = pl[(a + 3) * HL_];
        a0 = __builtin_fmaf(fast_tanh(p.x + l0), w4.x, a0);
        a1 = __builtin_fmaf(fast_tanh(p.y + l1), w4.y, a1);
        a2 = __builtin_fmaf(fast_tanh(p.z + l2), w4.z, a2);
        a3 = __builtin_fmaf(fast_tanh(p.w + l3), w4.w, a3);
    }
    float acc = (a0 + a1) + (a2 + a3);
    int mv = (lane < HL_) ? lmask[b * HL_ + lane] : 0;
    float logit = mv ? acc : -1e9f;            // b2 dropped: softmax-invariant
    float mx = logit;
#pragma unroll
    for (int o = 32; o > 0; o >>= 1) mx = fmaxf(mx, __shfl_xor(mx, o));
    float e = EXP2F((logit - mx) * 1.44269504f);   // masked lanes -> 0
    float s = e;
#pragma unroll
    for (int o = 32; o > 0; o >>= 1) s += __shfl_xor(s, o);
    at_s[wid][lane] = e * RCPF(s);
    // no barrier: same wave writes & reads its own slice (lgkmcnt enforced)

    // phase 2: out[b,n][d], d = lane + 64j (j<7); lf rows coalesced 128B (L2-hit).
    const u16* lfb = lf_bf + (size_t)b * HL_ * NEWS_DIM + lane;
    float acc7[7];
#pragma unroll
    for (int j = 0; j < 7; j++) acc7[j] = 0.f;
    for (int h = 0; h < HL_; h++) {
        float av = at_s[wid][h];               // LDS broadcast
        const u16* row = lfb + (size_t)h * NEWS_DIM;
#pragma unroll
        for (int j = 0; j < 7; j++)
            acc7[j] = fmaf(av, bf2f(row[64 * j]), acc7[j]);
    }
    float* o0 = out + (size_t)g * NEWS_DIM + lane;
#pragma unroll
    for (int j = 0; j < 7; j++) o0[64 * j] = acc7[j];
}

extern "C" void kernel_launch(void* const* d_in, const int* in_sizes, int n_in,
                              void* d_out, int out_size, void* d_ws, size_t ws_size,
                              hipStream_t stream) {
    const float* logv  = (const float*)d_in[0];  // (64,50,384) f32
    const int*   lmask = (const int*)d_in[1];    // (64,50) i32
    const float* newsv = (const float*)d_in[2];  // (64,64,384) f32
    const float* pos   = (const float*)d_in[3];  // (100,64) f32; row 0 == 0
    const float* W1    = (const float*)d_in[4];  // (256,896) f32
    const float* b1    = (const float*)d_in[5];  // (256,) f32
    const float* w2    = (const float*)d_in[6];  // (1,256) f32
    // b2 unused (softmax-invariant shift)

    float* out = (float*)d_out;                  // [user_log | nf], f32
    float* nf  = out + (size_t)B_ * NN_ * NEWS_DIM;

    // d_ws ~256 MiB. Byte offsets, 16B aligned:
    char* ws = (char*)d_ws;
    u16*   lf_bf = (u16*)(ws + 0);               // 3200x448 bf16  (2,867,200 B)
    u16*   Wbf   = (u16*)(ws + 2867200);         // 256x896 bf16   (458,752 B)
    u16*   nv_bf = (u16*)(ws + 3325952);         // 4096x384 bf16  (3,145,728 B)
    float* pn    = (float*)(ws + 6471680);       // 4096x256 f32   (4,194,304 B)
    float* plT   = (float*)(ws + 10665984);      // 64x256x50 f32  (3,276,800 B)

    prep_k    <<<C_TOT / 256, 256, 0, stream>>>(W1, newsv, logv, pos,
                                                Wbf, nv_bf, lf_bf, nf);
    gemm_k    <<<456, 64, 0, stream>>>(nv_bf, lf_bf, Wbf, b1, pn, plT);
    attn_out_k<<<1024, 256, 0, stream>>>(pn, plT, w2, lmask, lf_bf, out);
}